// Round 2
// baseline (539.382 us; speedup 1.0000x reference)
//
#include <hip/hip_runtime.h>
#include <cstdint>
#include <cstddef>

// ---------------- numeric constants (fp64, 17 sig digits) ----------------
// psp IIR: d = exp(-1/tau), c = e/tau   (alpha kernel k(t) = c * t * d^t)
#define D_TAU1 0.36787944117144233   // exp(-1)
#define C_TAU1 2.7182818284590452    // e
#define D_TAU2 0.60653065971263342   // exp(-1/2)
#define C_TAU2 1.3591409142295226    // e/2
#define D_TAU4 0.77880078307140487   // exp(-1/4)
#define C_TAU4 0.67957045711476131   // e/4
// refractory: dr = exp(-1/tauRef), d32 = dr^32, cr = -2*theta*scaleRef*e/tauRef
#define DR1   0.36787944117144233
#define D32_1 1.2664165549094176e-14 // exp(-32)
#define CR1   -163.09690970754271    // -60e   (theta=30, tauRef=1)
#define DR2   0.60653065971263342
#define D32_2 1.1253517471925911e-7  // exp(-16)
#define CR2   -135.91409142295226    // -50e   (theta=50, tauRef=2)
#define DR3   0.77880078307140487
#define D32_3 3.3546262790251184e-4  // exp(-8)
#define CR3   -135.91409142295226    // -50e   (theta=100, tauRef=4)

// SLAYER spike scan with KREF=32 truncated refractory kernel, done as
// full alpha-IIR minus a 32-step-delayed alpha-IIR (exact cancellation
// for spikes older than the window). hist doubles as the output bitmask.
// Contribution of spike at s to time t is r[t-s-1] (r[0]=0), matching the
// reference scan's post-read shift.
struct Spike { double Arf, Brf, Ad, Bd; unsigned long long hist; };

__device__ __forceinline__ double spike_step(Spike& st, double u, int t,
                                             double theta, double dr,
                                             double d32, double cr) {
  const double R = cr * (st.Brf - d32 * (st.Bd + 32.0 * st.Ad));
  const double v = u + R;
  const bool fire = (v >= theta);
  const double s = fire ? 1.0 : 0.0;
  st.Brf = dr * (st.Brf + st.Arf);
  st.Arf = dr * st.Arf + s;
  const double sd = (t >= 32) ? (double)((st.hist >> (t - 32)) & 1ull) : 0.0;
  st.Bd = dr * (st.Bd + st.Ad);
  st.Ad = dr * st.Ad + sd;
  if (fire) st.hist |= (1ull << t);
  return s;
}

// ---------------- geometry ----------------
// B=8, T=64. Workspace (42 MB total):
//   P1p: (16 img, 64 t, 68, 68) fp64, pad 2 zero border   37.9 MB
//   S1 : (64 img = b*8+o, 64*64 sites) uint64 spike masks  2 MB
//   S2 : (16 img = b*2+o, 128*128 sites) uint64 masks      2 MB
#define P1_IS (68 * 68)

// Zero the padding ring of every (img,t) plane. blockIdx.x = plane index.
__global__ void k_zero_border(double* __restrict__ buf, int rows, int cols, int pad) {
  double* img = buf + (size_t)blockIdx.x * rows * cols;
  const int inner = rows - 2 * pad;
  const int cA = pad * cols;       // top rows
  const int cC = inner * pad;      // left cols of middle
  const int total = 2 * cA + 2 * cC;
  for (int i = threadIdx.x; i < total; i += blockDim.x) {
    int r, c;
    if (i < cA)            { r = i / cols; c = i - r * cols; }
    else if (i < 2 * cA)   { int j = i - cA; int rr = j / cols; r = rows - pad + rr; c = j - rr * cols; }
    else if (i < 2*cA + cC){ int j = i - 2 * cA; int rr = j / pad; r = pad + rr; c = j - rr * pad; }
    else                   { int j = i - 2*cA - cC; int rr = j / pad; r = pad + rr; c = cols - pad + (j - rr * pad); }
    img[(size_t)r * cols + c] = 0.0;
  }
}

// K1: psp(spikeInput, tau=1) -> P1p interior, (B,C,H,W,T)->(img,t,y,x) transpose.
__global__ __launch_bounds__(256) void k_psp1(const float* __restrict__ x,
                                              double* __restrict__ p1) {
  const int idx = blockIdx.x * 256 + threadIdx.x;  // 65536 sites (b,c,y,x)
  const int xw = idx & 63;
  const int yy = (idx >> 6) & 63;
  const int bc = idx >> 12;
  const float* xin = x + (size_t)idx * 64;         // T contiguous
  double* op = p1 + ((size_t)bc * 64) * P1_IS + (size_t)(yy + 2) * 68 + (xw + 2);
  double A = 0.0, Bv = 0.0;
  for (int t4 = 0; t4 < 16; ++t4) {
    const float4 v = reinterpret_cast<const float4*>(xin)[t4];
    const float f[4] = {v.x, v.y, v.z, v.w};
#pragma unroll
    for (int k = 0; k < 4; ++k) {
      Bv = D_TAU1 * (Bv + A);
      A = D_TAU1 * A + (double)f[k];
      op[(size_t)(t4 * 4 + k) * P1_IS] = C_TAU1 * Bv;
    }
  }
}

// K2: conv5x5(psp1) -> spike(theta=30,tauRef=1) -> S1 bitmask.
__global__ __launch_bounds__(256) void k_conv1_spike(
    const double* __restrict__ p1, const float* __restrict__ w1f,
    unsigned long long* __restrict__ s1) {
  const int o = blockIdx.y;             // 0..7
  const int b = blockIdx.z;             // 0..7
  const int xw = threadIdx.x;           // 0..63
  const int yy = blockIdx.x * 4 + threadIdx.y;  // 0..63
  double w[50];
#pragma unroll
  for (int i = 0; i < 50; ++i) w[i] = (double)w1f[o * 50 + i];
  const double* b0 = p1 + ((size_t)(b * 2 + 0) * 64) * P1_IS + (size_t)yy * 68 + xw;
  const double* b1 = p1 + ((size_t)(b * 2 + 1) * 64) * P1_IS + (size_t)yy * 68 + xw;
  Spike st = {0.0, 0.0, 0.0, 0.0, 0ull};
  for (int t = 0; t < 64; ++t) {
    const double* q0 = b0 + (size_t)t * P1_IS;
    const double* q1 = b1 + (size_t)t * P1_IS;
    double u = 0.0;
#pragma unroll
    for (int ky = 0; ky < 5; ++ky) {
#pragma unroll
      for (int kx = 0; kx < 5; ++kx) {
        u = fma(w[ky * 5 + kx],      q0[(size_t)ky * 68 + kx], u);
        u = fma(w[25 + ky * 5 + kx], q1[(size_t)ky * 68 + kx], u);
      }
    }
    (void)spike_step(st, u, t, 30.0, DR1, D32_1, CR1);
  }
  s1[(size_t)(b * 8 + o) * 4096 + yy * 64 + xw] = st.hist;
}

// K3: deconv2x2-s2(psp(s1,tau=2)) -> spike(theta=50,tauRef=2) -> S2 bitmask.
// Non-overlapping deconv: each output site reads exactly one input site x 8 ch;
// psp2 recomputed in-register from the 8 spike masks.
__global__ __launch_bounds__(256) void k_deconv_spike(
    const unsigned long long* __restrict__ s1, const float* __restrict__ w2f,
    unsigned long long* __restrict__ s2) {
  const int X = threadIdx.x;                       // 0..127
  const int Y = blockIdx.x * 2 + threadIdx.y;      // 0..127
  const int o = blockIdx.y;                        // 0..1
  const int b = blockIdx.z;                        // 0..7
  const int xi = X >> 1, jj = X & 1, yi = Y >> 1, ii = Y & 1;
  double w[8];
  unsigned long long m[8];
#pragma unroll
  for (int c = 0; c < 8; ++c) {
    w[c] = (double)w2f[((c * 2 + o) * 2 + ii) * 2 + jj];
    m[c] = s1[(size_t)(b * 8 + c) * 4096 + yi * 64 + xi];
  }
  double A[8], Bv[8];
#pragma unroll
  for (int c = 0; c < 8; ++c) { A[c] = 0.0; Bv[c] = 0.0; }
  Spike st = {0.0, 0.0, 0.0, 0.0, 0ull};
  for (int t = 0; t < 64; ++t) {
    double u = 0.0;
#pragma unroll
    for (int c = 0; c < 8; ++c) {
      Bv[c] = D_TAU2 * (Bv[c] + A[c]);
      A[c] = D_TAU2 * A[c] + (double)((m[c] >> t) & 1ull);
      u = fma(w[c], C_TAU2 * Bv[c], u);
    }
    (void)spike_step(st, u, t, 50.0, DR2, D32_2, CR2);
  }
  s2[(size_t)(b * 2 + o) * 16384 + Y * 128 + X] = st.hist;
}

// K4: conv3x3(psp(s2,tau=4)) + bilinear2x(psp1) -> spike(theta=100,tauRef=4) -> out.
// 18 psp3-IIRs recomputed in-register from the 3x3x2 neighbor masks (OOB -> mask 0).
__global__ __launch_bounds__(256) void k_conv3_spike_out(
    const unsigned long long* __restrict__ s2, const float* __restrict__ w3f,
    const double* __restrict__ p1, float* __restrict__ out) {
  const int X = threadIdx.x;                       // 0..127
  const int Y = blockIdx.x * 2 + threadIdx.y;      // 0..127
  const int o = blockIdx.y;                        // 0..1
  const int b = blockIdx.z;                        // 0..7
  double w[18];
#pragma unroll
  for (int i = 0; i < 18; ++i) w[i] = (double)w3f[o * 18 + i];
  unsigned long long m[18];
#pragma unroll
  for (int cc = 0; cc < 2; ++cc) {
#pragma unroll
    for (int ky = 0; ky < 3; ++ky) {
#pragma unroll
      for (int kx = 0; kx < 3; ++kx) {
        const int yn = Y - 1 + ky, xn = X - 1 + kx;
        const bool ok = (yn >= 0) & (yn < 128) & (xn >= 0) & (xn < 128);
        m[cc * 9 + ky * 3 + kx] = ok ?
          s2[(size_t)(b * 2 + cc) * 16384 + yn * 128 + xn] : 0ull;
      }
    }
  }
  double A[18], Bv[18];
#pragma unroll
  for (int i = 0; i < 18; ++i) { A[i] = 0.0; Bv[i] = 0.0; }
  // bilinear 2x taps, half-pixel; edge handling == clamp
  const int y0 = (Y - 1) >> 1;
  const int x0 = (X - 1) >> 1;
  const double wy1 = (Y & 1) ? 0.25 : 0.75, wy0 = 1.0 - wy1;
  const double wx1 = (X & 1) ? 0.25 : 0.75, wx0 = 1.0 - wx1;
  const int iy0 = max(y0, 0), iy1 = min(y0 + 1, 63);
  const int ix0 = max(x0, 0), ix1 = min(x0 + 1, 63);
  const double* pu = p1 + ((size_t)(b * 2 + o) * 64) * P1_IS;
  const size_t a00 = (size_t)(iy0 + 2) * 68 + (ix0 + 2);
  const size_t a01 = (size_t)(iy0 + 2) * 68 + (ix1 + 2);
  const size_t a10 = (size_t)(iy1 + 2) * 68 + (ix0 + 2);
  const size_t a11 = (size_t)(iy1 + 2) * 68 + (ix1 + 2);
  Spike st = {0.0, 0.0, 0.0, 0.0, 0ull};
  for (int t = 0; t < 64; ++t) {
    double u = 0.0;
#pragma unroll
    for (int i = 0; i < 18; ++i) {
      Bv[i] = D_TAU4 * (Bv[i] + A[i]);
      A[i] = D_TAU4 * A[i] + (double)((m[i] >> t) & 1ull);
      u = fma(w[i], C_TAU4 * Bv[i], u);
    }
    const double* pt = pu + (size_t)t * P1_IS;
    u += wy0 * (wx0 * pt[a00] + wx1 * pt[a01]) +
         wy1 * (wx0 * pt[a10] + wx1 * pt[a11]);
    (void)spike_step(st, u, t, 100.0, DR3, D32_3, CR3);
  }
  float* op = out + (((size_t)(b * 2 + o) * 128 + Y) * 128 + X) * 64;
#pragma unroll
  for (int t4 = 0; t4 < 16; ++t4) {
    float4 v;
    v.x = ((st.hist >> (t4 * 4 + 0)) & 1ull) ? 1.0f : 0.0f;
    v.y = ((st.hist >> (t4 * 4 + 1)) & 1ull) ? 1.0f : 0.0f;
    v.z = ((st.hist >> (t4 * 4 + 2)) & 1ull) ? 1.0f : 0.0f;
    v.w = ((st.hist >> (t4 * 4 + 3)) & 1ull) ? 1.0f : 0.0f;
    reinterpret_cast<float4*>(op)[t4] = v;
  }
}

extern "C" void kernel_launch(void* const* d_in, const int* in_sizes, int n_in,
                              void* d_out, int out_size, void* d_ws, size_t ws_size,
                              hipStream_t stream) {
  const float* spikeIn = (const float*)d_in[0];   // (8,2,64,64,64) fp32
  const float* w1 = (const float*)d_in[1];        // (8,2,5,5)
  const float* w2 = (const float*)d_in[2];        // (8,2,2,2) = (in,out,i,j)
  const float* w3 = (const float*)d_in[3];        // (2,2,3,3)
  float* out = (float*)d_out;                     // (8,2,128,128,64) fp32

  double* P1p = (double*)d_ws;                               // 37.9 MB
  unsigned long long* S1 = (unsigned long long*)(P1p + (size_t)16 * 64 * P1_IS);
  unsigned long long* S2 = S1 + (size_t)64 * 4096;           // +2 MB, +2 MB

  // zero P1p padding ring (d_ws is re-poisoned before every launch)
  k_zero_border<<<dim3(16 * 64), dim3(128), 0, stream>>>(P1p, 68, 68, 2);
  // K1: psp1
  k_psp1<<<dim3(256), dim3(256), 0, stream>>>(spikeIn, P1p);
  // K2: conv5x5 + spike1 -> S1
  k_conv1_spike<<<dim3(16, 8, 8), dim3(64, 4), 0, stream>>>(P1p, w1, S1);
  // K3: deconv2x + spike2 -> S2
  k_deconv_spike<<<dim3(64, 2, 8), dim3(128, 2), 0, stream>>>(S1, w2, S2);
  // K4: conv3x3 + bilinear skip + spike3 -> out
  k_conv3_spike_out<<<dim3(64, 2, 8), dim3(128, 2), 0, stream>>>(S2, w3, P1p, out);
}